// Round 14
// baseline (278.861 us; speedup 1.0000x reference)
//
#include <hip/hip_runtime.h>
#include <hip/hip_fp16.h>
#include <cstdint>
#include <cstring>

typedef unsigned int uint;

#define BSHIFT 8          // 256 nodes per bucket
#define NBUCK 512         // max buckets (N up to 131072)
#define TILE 8192         // kb_scatter tile (16 edges/thread x 512)
#define SCAT_T 512
#define SORT_T 512
#define SORT_CAP 5120     // per-bucket capacity (mean ~4092, +16 sigma)

__device__ __forceinline__ float leaky02(float x) { return x > 0.f ? x : 0.2f * x; }
__device__ __forceinline__ float bflo(uint u) { return __uint_as_float(u << 16); }
__device__ __forceinline__ float bfhi(uint u) { return __uint_as_float(u & 0xffff0000u); }

__device__ __forceinline__ uint pack_bf16x2(float a, float b) {
    uint ua = __float_as_uint(a), ub = __float_as_uint(b);
    ua += 0x7fffu + ((ua >> 16) & 1u);
    ub += 0x7fffu + ((ub >> 16) & 1u);
    return (ua >> 16) | (ub & 0xffff0000u);
}

__device__ __forceinline__ uint packh2(float a, float b) {
    __half ha = __float2half_rn(a), hb = __float2half_rn(b);
    unsigned short ua, ub;
    memcpy(&ua, &ha, 2);
    memcpy(&ub, &hb, 2);
    return (uint)ua | ((uint)ub << 16);
}

// ---------------------------------------------------------------------------
// Kernel A: h = x @ W_lin (bf16x2), a_src/a_dst per head. Block 0 zero-inits
// cursor/sums/sumsq.
// ---------------------------------------------------------------------------
__global__ void k_linear(const float* __restrict__ x, const float* __restrict__ W,
                         const float* __restrict__ att_s, const float* __restrict__ att_d,
                         uint* __restrict__ h, float* __restrict__ a_src,
                         float* __restrict__ a_dst, int N,
                         int* __restrict__ cursor, float* __restrict__ sums,
                         float* __restrict__ sumsq) {
    if (blockIdx.x == 0) {
        int t = threadIdx.x;
        cursor[t] = 0;
        cursor[t + 256] = 0;
        if (t < 128) { sums[t] = 0.f; sumsq[t] = 0.f; }
    }
    int lane = threadIdx.x & 63;
    int n = blockIdx.x * 4 + (threadIdx.x >> 6);
    if (n >= N) return;
    const float* xr = x + (size_t)n * 16;
    float xv = xr[lane & 15];
    float acc0 = 0.f, acc1 = 0.f;
#pragma unroll
    for (int k = 0; k < 16; k++) {
        float xk = __shfl(xv, k);
        float2 w = ((const float2*)(W + k * 128))[lane];
        acc0 += xk * w.x;
        acc1 += xk * w.y;
    }
    h[(size_t)n * 64 + lane] = pack_bf16x2(acc0, acc1);
    float2 as = ((const float2*)att_s)[lane];
    float2 ad = ((const float2*)att_d)[lane];
    float ps = acc0 * as.x + acc1 * as.y;
    float pd = acc0 * ad.x + acc1 * ad.y;
#pragma unroll
    for (int off = 8; off >= 1; off >>= 1) {
        ps += __shfl_xor(ps, off);
        pd += __shfl_xor(pd, off);
    }
    if ((lane & 15) == 0) {
        a_src[n * 4 + (lane >> 4)] = ps;
        a_dst[n * 4 + (lane >> 4)] = pd;
    }
}

// ---------------------------------------------------------------------------
// Scatter into capacity buckets: bucket b owns pairs[b*SORT_CAP ...].
// LDS-staged for dense bucket-contiguous writes. code = (src<<8)|(dst&255).
// TILE=8192 (16 edges/thread) halves the number of per-tile scans.
// ---------------------------------------------------------------------------
__global__ void kb_scatter(const int* __restrict__ src, const int* __restrict__ dst, int E,
                           int* __restrict__ cursor, uint* __restrict__ pairs) {
    __shared__ int tileCnt[NBUCK], tileCnt2[NBUCK], tileOff[NBUCK], gbase[NBUCK];
    __shared__ int sA[NBUCK], sB[NBUCK];
    __shared__ uint lp[TILE];
    __shared__ unsigned short lb[TILE];
    int tid = threadIdx.x;  // 512
    int t0 = blockIdx.x * TILE;
    tileCnt[tid] = 0;
    tileCnt2[tid] = 0;
    __syncthreads();
    int dreg[16], sreg[16];
#pragma unroll
    for (int j = 0; j < 16; j++) {
        int idx = t0 + j * SCAT_T + tid;
        if (idx < E) {
            dreg[j] = dst[idx];
            sreg[j] = src[idx];
            atomicAdd(&tileCnt[dreg[j] >> BSHIFT], 1);
        } else dreg[j] = -1;
    }
    __syncthreads();
    int* a = sA; int* b = sB;
    a[tid] = tileCnt[tid];
    __syncthreads();
    for (int off = 1; off < NBUCK; off <<= 1) {
        b[tid] = a[tid] + (tid >= off ? a[tid - off] : 0);
        __syncthreads();
        int* t = a; a = b; b = t;
    }
    tileOff[tid] = a[tid] - tileCnt[tid];
    if (tileCnt[tid] > 0) gbase[tid] = atomicAdd(&cursor[tid], tileCnt[tid]);
    __syncthreads();
#pragma unroll
    for (int j = 0; j < 16; j++) {
        if (dreg[j] >= 0) {
            int bk = dreg[j] >> BSHIFT;
            int r = atomicAdd(&tileCnt2[bk], 1);
            int pos = tileOff[bk] + r;
            lp[pos] = ((uint)sreg[j] << BSHIFT) | (uint)(dreg[j] & 255);
            lb[pos] = (unsigned short)bk;
        }
    }
    __syncthreads();
    int tot = min(TILE, E - t0);
    for (int k = tid; k < tot; k += SCAT_T) {
        int bk = lb[k];
        int lpos = gbase[bk] + (k - tileOff[bk]);
        if (lpos < SORT_CAP)
            pairs[(size_t)bk * SORT_CAP + lpos] = lp[k];
    }
}

// ---------------------------------------------------------------------------
// Per-bucket counting sort + per-edge weight precompute.
// Emits sorted[] (src) and wsorted[] (fp16x4 weights), both coalesced.
// a_dst slice staged in LDS.
// ---------------------------------------------------------------------------
__global__ void kb_sort(const uint* __restrict__ pairs, const int* __restrict__ cursor,
                        const float* __restrict__ a_src, const float* __restrict__ a_dst,
                        int N,
                        int* __restrict__ sorted, uint2* __restrict__ wsorted,
                        int* __restrict__ offsets, int* __restrict__ degs) {
    __shared__ int cnt[256], off0[256], sA[256], sB[256];
    __shared__ uint lcode[SORT_CAP];
    __shared__ float4 sad[256];
    int tid = threadIdx.x;  // 512
    int b = blockIdx.x;
    int n0 = b << BSHIFT;
    int nn = min(256, N - n0);
    int ebase = b * SORT_CAP;
    int ecnt = cursor[b];
    if (ecnt > SORT_CAP) ecnt = SORT_CAP;
    if (tid < 256) cnt[tid] = 0;
    if (tid < nn) sad[tid] = ((const float4*)a_dst)[n0 + tid];
    __syncthreads();
    for (int k = tid; k < ecnt; k += SORT_T)
        atomicAdd(&cnt[pairs[ebase + k] & 255], 1);
    __syncthreads();
    int v = 0;
    int* a = sA; int* bb = sB;
    if (tid < 256) { v = cnt[tid]; a[tid] = v; }
    __syncthreads();
    for (int off = 1; off < 256; off <<= 1) {
        if (tid < 256) bb[tid] = a[tid] + (tid >= off ? a[tid - off] : 0);
        __syncthreads();
        int* t = a; a = bb; bb = t;
    }
    if (tid < 256) off0[tid] = a[tid] - v;
    __syncthreads();
    if (tid < 256) cnt[tid] = 0;
    __syncthreads();
    for (int k = tid; k < ecnt; k += SORT_T) {
        uint p = pairs[ebase + k];
        int ln = p & 255;
        int r = atomicAdd(&cnt[ln], 1);
        lcode[off0[ln] + r] = p;
    }
    __syncthreads();
    // pass 2: in-order, fully coalesced emit
    for (int k = tid; k < ecnt; k += SORT_T) {
        uint p = lcode[k];
        int src = (int)(p >> BSHIFT);
        int ln = p & 255;
        sorted[ebase + k] = src;
        float4 as = ((const float4*)a_src)[src];
        float4 ad = sad[ln];
        float w0 = __expf(leaky02(as.x + ad.x));
        float w1 = __expf(leaky02(as.y + ad.y));
        float w2 = __expf(leaky02(as.z + ad.z));
        float w3 = __expf(leaky02(as.w + ad.w));
        wsorted[ebase + k] = make_uint2(packh2(w0, w1), packh2(w2, w3));
    }
    if (tid < nn) {
        offsets[n0 + tid] = ebase + off0[tid];
        degs[n0 + tid] = v;
    }
}

// ---------------------------------------------------------------------------
// GAT aggregation: 4 nodes per wave, 16 lanes per node (8 ch/lane, uint4).
// Unroll x8: 8 edges in flight per node group (32 outstanding gathers/wave).
// No cross-lane merges; weight-sum accumulated redundantly per lane.
// ---------------------------------------------------------------------------
__global__ void k_gat(const int* __restrict__ offsets, const int* __restrict__ degs,
                      const int* __restrict__ sorted, const uint2* __restrict__ wsorted,
                      const uint* __restrict__ h, const float* __restrict__ a_src,
                      const float* __restrict__ a_dst, const float* __restrict__ bias,
                      uint* __restrict__ hagg, int N) {
    int nb = gridDim.x;
    int g = nb >> 3;
    int bi = blockIdx.x;
    int blk = (bi < (g << 3)) ? ((bi & 7) * g + (bi >> 3)) : bi;
    int lane = threadIdx.x & 63;
    int wid = threadIdx.x >> 6;
    int q = lane >> 4;      // node group within wave
    int l16 = lane & 15;    // channel group: 8 channels (uint4)
    int head = l16 >> 2;
    int d = blk * 16 + wid * 4 + q;
    if (d >= N) return;
    int base = offsets[d];
    int deg = degs[d];

    const int* sp = sorted + base;
    const __half* wp = (const __half*)(wsorted + base) + head;

    // self loop
    float w = __expf(leaky02(a_src[d * 4 + head] + a_dst[d * 4 + head]));
    uint4 u = ((const uint4*)(h + (size_t)d * 64))[l16];
    float sum = w;
    float2 a01 = make_float2(w * bflo(u.x), w * bfhi(u.x));
    float2 a23 = make_float2(w * bflo(u.y), w * bfhi(u.y));
    float2 a45 = make_float2(w * bflo(u.z), w * bfhi(u.z));
    float2 a67 = make_float2(w * bflo(u.w), w * bfhi(u.w));

    int i = 0;
    for (; i + 7 < deg; i += 8) {
        int s[8];
        float wv[8];
        uint4 uu[8];
#pragma unroll
        for (int j = 0; j < 8; j++) s[j] = sp[i + j];
#pragma unroll
        for (int j = 0; j < 8; j++) wv[j] = __half2float(wp[(i + j) * 4]);
#pragma unroll
        for (int j = 0; j < 8; j++) uu[j] = ((const uint4*)(h + (size_t)s[j] * 64))[l16];
#pragma unroll
        for (int j = 0; j < 8; j++) {
            sum += wv[j];
            float2 wj = {wv[j], wv[j]};
            a01 += make_float2(bflo(uu[j].x), bfhi(uu[j].x)) * wj;
            a23 += make_float2(bflo(uu[j].y), bfhi(uu[j].y)) * wj;
            a45 += make_float2(bflo(uu[j].z), bfhi(uu[j].z)) * wj;
            a67 += make_float2(bflo(uu[j].w), bfhi(uu[j].w)) * wj;
        }
    }
    for (; i + 3 < deg; i += 4) {
        int s[4];
        float wv[4];
        uint4 uu[4];
#pragma unroll
        for (int j = 0; j < 4; j++) s[j] = sp[i + j];
#pragma unroll
        for (int j = 0; j < 4; j++) wv[j] = __half2float(wp[(i + j) * 4]);
#pragma unroll
        for (int j = 0; j < 4; j++) uu[j] = ((const uint4*)(h + (size_t)s[j] * 64))[l16];
#pragma unroll
        for (int j = 0; j < 4; j++) {
            sum += wv[j];
            float2 wj = {wv[j], wv[j]};
            a01 += make_float2(bflo(uu[j].x), bfhi(uu[j].x)) * wj;
            a23 += make_float2(bflo(uu[j].y), bfhi(uu[j].y)) * wj;
            a45 += make_float2(bflo(uu[j].z), bfhi(uu[j].z)) * wj;
            a67 += make_float2(bflo(uu[j].w), bfhi(uu[j].w)) * wj;
        }
    }
    for (; i < deg; i++) {
        int s0 = sp[i];
        float w0 = __half2float(wp[i * 4]);
        uint4 u0 = ((const uint4*)(h + (size_t)s0 * 64))[l16];
        sum += w0;
        float2 w02 = {w0, w0};
        a01 += make_float2(bflo(u0.x), bfhi(u0.x)) * w02;
        a23 += make_float2(bflo(u0.y), bfhi(u0.y)) * w02;
        a45 += make_float2(bflo(u0.z), bfhi(u0.z)) * w02;
        a67 += make_float2(bflo(u0.w), bfhi(u0.w)) * w02;
    }
    float inv = 1.f / sum;
    float4 b0 = ((const float4*)bias)[2 * l16];
    float4 b1 = ((const float4*)bias)[2 * l16 + 1];
    uint4 o;
    o.x = pack_bf16x2(a01.x * inv + b0.x, a01.y * inv + b0.y);
    o.y = pack_bf16x2(a23.x * inv + b0.z, a23.y * inv + b0.w);
    o.z = pack_bf16x2(a45.x * inv + b1.x, a45.y * inv + b1.y);
    o.w = pack_bf16x2(a67.x * inv + b1.z, a67.y * inv + b1.w);
    ((uint4*)(hagg + (size_t)d * 64))[l16] = o;
}

// ---------------------------------------------------------------------------
// BN column sums / sums-of-squares over bf16 [N,128]
// ---------------------------------------------------------------------------
__global__ void k_bnstats(const uint* __restrict__ hagg, int N,
                          float* __restrict__ sums, float* __restrict__ sumsq) {
    int t = threadIdx.x;
    int cg = t & 31, rs = t >> 5;
    float4 s = make_float4(0.f, 0.f, 0.f, 0.f), q = make_float4(0.f, 0.f, 0.f, 0.f);
    for (int n = blockIdx.x * 8 + rs; n < N; n += gridDim.x * 8) {
        uint2 u = ((const uint2*)(hagg + (size_t)n * 64))[cg];
        float v0 = bflo(u.x), v1 = bfhi(u.x), v2 = bflo(u.y), v3 = bfhi(u.y);
        s.x += v0; s.y += v1; s.z += v2; s.w += v3;
        q.x += v0 * v0; q.y += v1 * v1; q.z += v2 * v2; q.w += v3 * v3;
    }
    __shared__ float4 ls[256], lq[256];
    ls[t] = s; lq[t] = q;
    __syncthreads();
    if (t < 32) {
        float4 S = ls[t], Q = lq[t];
        for (int r = 1; r < 8; r++) {
            float4 a = ls[t + r * 32], b = lq[t + r * 32];
            S.x += a.x; S.y += a.y; S.z += a.z; S.w += a.w;
            Q.x += b.x; Q.y += b.y; Q.z += b.z; Q.w += b.w;
        }
        atomicAdd(&sums[t * 4 + 0], S.x);
        atomicAdd(&sums[t * 4 + 1], S.y);
        atomicAdd(&sums[t * 4 + 2], S.z);
        atomicAdd(&sums[t * 4 + 3], S.w);
        atomicAdd(&sumsq[t * 4 + 0], Q.x);
        atomicAdd(&sumsq[t * 4 + 1], Q.y);
        atomicAdd(&sumsq[t * 4 + 2], Q.z);
        atomicAdd(&sumsq[t * 4 + 3], Q.w);
    }
}

// ---------------------------------------------------------------------------
// Per LUT node: BN + ReLU + MLP 128->32 (leaky 0.01) -> 1
// ---------------------------------------------------------------------------
__global__ void k_mlp(const uint* __restrict__ hagg, const int* __restrict__ lut,
                      const float* __restrict__ sums, const float* __restrict__ sumsq,
                      const float* __restrict__ gamma, const float* __restrict__ beta,
                      const float* __restrict__ W1, const float* __restrict__ b1,
                      const float* __restrict__ W2, const float* __restrict__ b2,
                      float* __restrict__ out, int N, int nlut) {
    int blk = blockIdx.x;
    if (blk >= nlut) return;
    int node = lut[blk];
    int lane = threadIdx.x;  // 64
    __shared__ float v[128];
    float invN = 1.f / (float)N;
    uint u = hagg[(size_t)node * 64 + lane];
    int c0 = 2 * lane, c1 = 2 * lane + 1;
    {
        float mean = sums[c0] * invN;
        float var = sumsq[c0] * invN - mean * mean;
        float val = (bflo(u) - mean) / sqrtf(var + 1e-5f) * gamma[c0] + beta[c0];
        v[c0] = fmaxf(val, 0.f);
        mean = sums[c1] * invN;
        var = sumsq[c1] * invN - mean * mean;
        val = (bfhi(u) - mean) / sqrtf(var + 1e-5f) * gamma[c1] + beta[c1];
        v[c1] = fmaxf(val, 0.f);
    }
    __syncthreads();
    float r = 0.f;
    if (lane < 32) {
        float z = b1[lane];
        for (int c = 0; c < 128; c++) z += v[c] * W1[c * 32 + lane];
        z = z > 0.f ? z : 0.01f * z;
        r = z * W2[lane];
    }
#pragma unroll
    for (int off = 16; off >= 1; off >>= 1) r += __shfl_xor(r, off);
    if (lane == 0) out[blk] = r + b2[0];
}

// ---------------------------------------------------------------------------
extern "C" void kernel_launch(void* const* d_in, const int* in_sizes, int n_in,
                              void* d_out, int out_size, void* d_ws, size_t ws_size,
                              hipStream_t stream) {
    const float* x     = (const float*)d_in[0];
    const int*   edges = (const int*)d_in[1];
    const int*   lut   = (const int*)d_in[2];
    const float* W_lin = (const float*)d_in[3];
    const float* att_s = (const float*)d_in[4];
    const float* att_d = (const float*)d_in[5];
    const float* bias  = (const float*)d_in[6];
    const float* gamma = (const float*)d_in[7];
    const float* beta  = (const float*)d_in[8];
    const float* W1    = (const float*)d_in[9];
    const float* b1    = (const float*)d_in[10];
    const float* W2    = (const float*)d_in[11];
    const float* b2    = (const float*)d_in[12];

    int N = in_sizes[0] / 16;
    int E = in_sizes[1] / 2;
    int nlut = in_sizes[2];
    int B = (N + 255) >> BSHIFT;   // 391 for N=100000

    const int* esrc = edges;
    const int* edst = edges + E;

    char* ws = (char*)d_ws;
    size_t off = 0;
    auto alloc = [&](size_t bytes) -> void* {
        void* p = ws + off;
        off += (bytes + 255) & ~(size_t)255;
        return p;
    };
    uint*  h       = (uint*)alloc((size_t)N * 64 * 4);          // bf16x2 [N,128]
    uint*  hagg    = (uint*)alloc((size_t)N * 64 * 4);          // bf16x2 [N,128]
    float* a_src   = (float*)alloc((size_t)N * 4 * 4);
    float* a_dst   = (float*)alloc((size_t)N * 4 * 4);
    int*   offsets = (int*)alloc((size_t)N * 4);
    int*   degs    = (int*)alloc((size_t)N * 4);
    int*   sorted  = (int*)alloc((size_t)B * SORT_CAP * 4);
    uint2* wsorted = (uint2*)alloc((size_t)B * SORT_CAP * 8);   // fp16x4 weights
    uint*  pairs   = (uint*)alloc((size_t)B * SORT_CAP * 4);
    int*   cursor  = (int*)alloc((size_t)NBUCK * 4);
    float* sums    = (float*)alloc(128 * 4);
    float* sumsq   = (float*)alloc(128 * 4);

    k_linear<<<(N + 3) / 4, 256, 0, stream>>>(x, W_lin, att_s, att_d, h, a_src, a_dst, N,
                                              cursor, sums, sumsq);
    kb_scatter<<<(E + TILE - 1) / TILE, SCAT_T, 0, stream>>>(esrc, edst, E, cursor, pairs);
    kb_sort<<<B, SORT_T, 0, stream>>>(pairs, cursor, a_src, a_dst, N,
                                      sorted, wsorted, offsets, degs);
    k_gat<<<(N + 15) / 16, 256, 0, stream>>>(offsets, degs, sorted, wsorted, h,
                                             a_src, a_dst, bias, hagg, N);
    k_bnstats<<<256, 256, 0, stream>>>(hagg, N, sums, sumsq);
    k_mlp<<<nlut, 64, 0, stream>>>(hagg, lut, sums, sumsq, gamma, beta, W1, b1, W2, b2,
                                   (float*)d_out, N, nlut);
}

// Round 15
// 278.323 us; speedup vs baseline: 1.0019x; 1.0019x over previous
//
#include <hip/hip_runtime.h>
#include <hip/hip_fp16.h>
#include <cstdint>
#include <cstring>

typedef unsigned int uint;

#define BSHIFT 8          // 256 nodes per bucket
#define NBUCK 512         // max buckets (N up to 131072)
#define TILE 4096         // kb_scatter tile
#define SCAT_T 512
#define SORT_T 512
#define SORT_CAP 5120     // per-bucket capacity (mean ~4092, +16 sigma)

__device__ __forceinline__ float leaky02(float x) { return x > 0.f ? x : 0.2f * x; }
__device__ __forceinline__ float bflo(uint u) { return __uint_as_float(u << 16); }
__device__ __forceinline__ float bfhi(uint u) { return __uint_as_float(u & 0xffff0000u); }

__device__ __forceinline__ uint pack_bf16x2(float a, float b) {
    uint ua = __float_as_uint(a), ub = __float_as_uint(b);
    ua += 0x7fffu + ((ua >> 16) & 1u);
    ub += 0x7fffu + ((ub >> 16) & 1u);
    return (ua >> 16) | (ub & 0xffff0000u);
}

__device__ __forceinline__ uint packh2(float a, float b) {
    __half ha = __float2half_rn(a), hb = __float2half_rn(b);
    unsigned short ua, ub;
    memcpy(&ua, &ha, 2);
    memcpy(&ub, &hb, 2);
    return (uint)ua | ((uint)ub << 16);
}

// ---------------------------------------------------------------------------
// Kernel A: h = x @ W_lin (bf16x2), a_src/a_dst per head. Block 0 zero-inits
// cursor/sums/sumsq.
// ---------------------------------------------------------------------------
__global__ void k_linear(const float* __restrict__ x, const float* __restrict__ W,
                         const float* __restrict__ att_s, const float* __restrict__ att_d,
                         uint* __restrict__ h, float* __restrict__ a_src,
                         float* __restrict__ a_dst, int N,
                         int* __restrict__ cursor, float* __restrict__ sums,
                         float* __restrict__ sumsq) {
    if (blockIdx.x == 0) {
        int t = threadIdx.x;
        cursor[t] = 0;
        cursor[t + 256] = 0;
        if (t < 128) { sums[t] = 0.f; sumsq[t] = 0.f; }
    }
    int lane = threadIdx.x & 63;
    int n = blockIdx.x * 4 + (threadIdx.x >> 6);
    if (n >= N) return;
    const float* xr = x + (size_t)n * 16;
    float xv = xr[lane & 15];
    float acc0 = 0.f, acc1 = 0.f;
#pragma unroll
    for (int k = 0; k < 16; k++) {
        float xk = __shfl(xv, k);
        float2 w = ((const float2*)(W + k * 128))[lane];
        acc0 += xk * w.x;
        acc1 += xk * w.y;
    }
    h[(size_t)n * 64 + lane] = pack_bf16x2(acc0, acc1);
    float2 as = ((const float2*)att_s)[lane];
    float2 ad = ((const float2*)att_d)[lane];
    float ps = acc0 * as.x + acc1 * as.y;
    float pd = acc0 * ad.x + acc1 * ad.y;
#pragma unroll
    for (int off = 8; off >= 1; off >>= 1) {
        ps += __shfl_xor(ps, off);
        pd += __shfl_xor(pd, off);
    }
    if ((lane & 15) == 0) {
        a_src[n * 4 + (lane >> 4)] = ps;
        a_dst[n * 4 + (lane >> 4)] = pd;
    }
}

// ---------------------------------------------------------------------------
// Scatter into capacity buckets: bucket b owns pairs[b*SORT_CAP ...].
// LDS-staged for dense bucket-contiguous writes. code = (src<<8)|(dst&255).
// ---------------------------------------------------------------------------
__global__ void kb_scatter(const int* __restrict__ src, const int* __restrict__ dst, int E,
                           int* __restrict__ cursor, uint* __restrict__ pairs) {
    __shared__ int tileCnt[NBUCK], tileCnt2[NBUCK], tileOff[NBUCK], gbase[NBUCK];
    __shared__ int sA[NBUCK], sB[NBUCK];
    __shared__ uint lp[TILE];
    __shared__ unsigned short lb[TILE];
    int tid = threadIdx.x;  // 512
    int t0 = blockIdx.x * TILE;
    tileCnt[tid] = 0;
    tileCnt2[tid] = 0;
    __syncthreads();
    int dreg[8], sreg[8];
#pragma unroll
    for (int j = 0; j < 8; j++) {
        int idx = t0 + j * SCAT_T + tid;
        if (idx < E) {
            dreg[j] = dst[idx];
            sreg[j] = src[idx];
            atomicAdd(&tileCnt[dreg[j] >> BSHIFT], 1);
        } else dreg[j] = -1;
    }
    __syncthreads();
    int* a = sA; int* b = sB;
    a[tid] = tileCnt[tid];
    __syncthreads();
    for (int off = 1; off < NBUCK; off <<= 1) {
        b[tid] = a[tid] + (tid >= off ? a[tid - off] : 0);
        __syncthreads();
        int* t = a; a = b; b = t;
    }
    tileOff[tid] = a[tid] - tileCnt[tid];
    if (tileCnt[tid] > 0) gbase[tid] = atomicAdd(&cursor[tid], tileCnt[tid]);
    __syncthreads();
#pragma unroll
    for (int j = 0; j < 8; j++) {
        if (dreg[j] >= 0) {
            int bk = dreg[j] >> BSHIFT;
            int r = atomicAdd(&tileCnt2[bk], 1);
            int pos = tileOff[bk] + r;
            lp[pos] = ((uint)sreg[j] << BSHIFT) | (uint)(dreg[j] & 255);
            lb[pos] = (unsigned short)bk;
        }
    }
    __syncthreads();
    int tot = min(TILE, E - t0);
    for (int k = tid; k < tot; k += SCAT_T) {
        int bk = lb[k];
        int lpos = gbase[bk] + (k - tileOff[bk]);
        if (lpos < SORT_CAP)
            pairs[(size_t)bk * SORT_CAP + lpos] = lp[k];
    }
}

// ---------------------------------------------------------------------------
// Per-bucket counting sort + per-edge weight precompute.
// Emits sorted[] (src) and wsorted[] (fp16x4 weights), both coalesced.
// a_dst slice staged in LDS.
// ---------------------------------------------------------------------------
__global__ void kb_sort(const uint* __restrict__ pairs, const int* __restrict__ cursor,
                        const float* __restrict__ a_src, const float* __restrict__ a_dst,
                        int N,
                        int* __restrict__ sorted, uint2* __restrict__ wsorted,
                        int* __restrict__ offsets, int* __restrict__ degs) {
    __shared__ int cnt[256], off0[256], sA[256], sB[256];
    __shared__ uint lcode[SORT_CAP];
    __shared__ float4 sad[256];
    int tid = threadIdx.x;  // 512
    int b = blockIdx.x;
    int n0 = b << BSHIFT;
    int nn = min(256, N - n0);
    int ebase = b * SORT_CAP;
    int ecnt = cursor[b];
    if (ecnt > SORT_CAP) ecnt = SORT_CAP;
    if (tid < 256) cnt[tid] = 0;
    if (tid < nn) sad[tid] = ((const float4*)a_dst)[n0 + tid];
    __syncthreads();
    for (int k = tid; k < ecnt; k += SORT_T)
        atomicAdd(&cnt[pairs[ebase + k] & 255], 1);
    __syncthreads();
    int v = 0;
    int* a = sA; int* bb = sB;
    if (tid < 256) { v = cnt[tid]; a[tid] = v; }
    __syncthreads();
    for (int off = 1; off < 256; off <<= 1) {
        if (tid < 256) bb[tid] = a[tid] + (tid >= off ? a[tid - off] : 0);
        __syncthreads();
        int* t = a; a = bb; bb = t;
    }
    if (tid < 256) off0[tid] = a[tid] - v;
    __syncthreads();
    if (tid < 256) cnt[tid] = 0;
    __syncthreads();
    for (int k = tid; k < ecnt; k += SORT_T) {
        uint p = pairs[ebase + k];
        int ln = p & 255;
        int r = atomicAdd(&cnt[ln], 1);
        lcode[off0[ln] + r] = p;
    }
    __syncthreads();
    // pass 2: in-order, fully coalesced emit
    for (int k = tid; k < ecnt; k += SORT_T) {
        uint p = lcode[k];
        int src = (int)(p >> BSHIFT);
        int ln = p & 255;
        sorted[ebase + k] = src;
        float4 as = ((const float4*)a_src)[src];
        float4 ad = sad[ln];
        float w0 = __expf(leaky02(as.x + ad.x));
        float w1 = __expf(leaky02(as.y + ad.y));
        float w2 = __expf(leaky02(as.z + ad.z));
        float w3 = __expf(leaky02(as.w + ad.w));
        wsorted[ebase + k] = make_uint2(packh2(w0, w1), packh2(w2, w3));
    }
    if (tid < nn) {
        offsets[n0 + tid] = ebase + off0[tid];
        degs[n0 + tid] = v;
    }
}

// ---------------------------------------------------------------------------
// GAT aggregation: 4 nodes per wave, 16 lanes per node (8 ch/lane, uint4).
// Unroll x4: 4 edges in flight per node group (16 outstanding gathers/wave).
// No cross-lane merges; weight-sum accumulated redundantly per lane.
// ---------------------------------------------------------------------------
__global__ void k_gat(const int* __restrict__ offsets, const int* __restrict__ degs,
                      const int* __restrict__ sorted, const uint2* __restrict__ wsorted,
                      const uint* __restrict__ h, const float* __restrict__ a_src,
                      const float* __restrict__ a_dst, const float* __restrict__ bias,
                      uint* __restrict__ hagg, int N) {
    int nb = gridDim.x;
    int g = nb >> 3;
    int bi = blockIdx.x;
    int blk = (bi < (g << 3)) ? ((bi & 7) * g + (bi >> 3)) : bi;
    int lane = threadIdx.x & 63;
    int wid = threadIdx.x >> 6;
    int q = lane >> 4;      // node group within wave
    int l16 = lane & 15;    // channel group: 8 channels (uint4)
    int head = l16 >> 2;
    int d = blk * 16 + wid * 4 + q;
    if (d >= N) return;
    int base = offsets[d];
    int deg = degs[d];

    const int* sp = sorted + base;
    const __half* wp = (const __half*)(wsorted + base) + head;

    // self loop
    float w = __expf(leaky02(a_src[d * 4 + head] + a_dst[d * 4 + head]));
    uint4 u = ((const uint4*)(h + (size_t)d * 64))[l16];
    float sum = w;
    float2 a01 = make_float2(w * bflo(u.x), w * bfhi(u.x));
    float2 a23 = make_float2(w * bflo(u.y), w * bfhi(u.y));
    float2 a45 = make_float2(w * bflo(u.z), w * bfhi(u.z));
    float2 a67 = make_float2(w * bflo(u.w), w * bfhi(u.w));

    int i = 0;
    for (; i + 3 < deg; i += 4) {
        int s0 = sp[i];
        int s1 = sp[i + 1];
        int s2 = sp[i + 2];
        int s3 = sp[i + 3];
        float w0 = __half2float(wp[i * 4]);
        float w1 = __half2float(wp[(i + 1) * 4]);
        float w2 = __half2float(wp[(i + 2) * 4]);
        float w3 = __half2float(wp[(i + 3) * 4]);
        uint4 u0 = ((const uint4*)(h + (size_t)s0 * 64))[l16];
        uint4 u1 = ((const uint4*)(h + (size_t)s1 * 64))[l16];
        uint4 u2 = ((const uint4*)(h + (size_t)s2 * 64))[l16];
        uint4 u3 = ((const uint4*)(h + (size_t)s3 * 64))[l16];
        sum += (w0 + w1) + (w2 + w3);
        float2 w02 = {w0, w0}, w12 = {w1, w1}, w22 = {w2, w2}, w32 = {w3, w3};
        a01 += make_float2(bflo(u0.x), bfhi(u0.x)) * w02
             + make_float2(bflo(u1.x), bfhi(u1.x)) * w12
             + make_float2(bflo(u2.x), bfhi(u2.x)) * w22
             + make_float2(bflo(u3.x), bfhi(u3.x)) * w32;
        a23 += make_float2(bflo(u0.y), bfhi(u0.y)) * w02
             + make_float2(bflo(u1.y), bfhi(u1.y)) * w12
             + make_float2(bflo(u2.y), bfhi(u2.y)) * w22
             + make_float2(bflo(u3.y), bfhi(u3.y)) * w32;
        a45 += make_float2(bflo(u0.z), bfhi(u0.z)) * w02
             + make_float2(bflo(u1.z), bfhi(u1.z)) * w12
             + make_float2(bflo(u2.z), bfhi(u2.z)) * w22
             + make_float2(bflo(u3.z), bfhi(u3.z)) * w32;
        a67 += make_float2(bflo(u0.w), bfhi(u0.w)) * w02
             + make_float2(bflo(u1.w), bfhi(u1.w)) * w12
             + make_float2(bflo(u2.w), bfhi(u2.w)) * w22
             + make_float2(bflo(u3.w), bfhi(u3.w)) * w32;
    }
    for (; i < deg; i++) {
        int s0 = sp[i];
        float w0 = __half2float(wp[i * 4]);
        uint4 u0 = ((const uint4*)(h + (size_t)s0 * 64))[l16];
        sum += w0;
        float2 w02 = {w0, w0};
        a01 += make_float2(bflo(u0.x), bfhi(u0.x)) * w02;
        a23 += make_float2(bflo(u0.y), bfhi(u0.y)) * w02;
        a45 += make_float2(bflo(u0.z), bfhi(u0.z)) * w02;
        a67 += make_float2(bflo(u0.w), bfhi(u0.w)) * w02;
    }
    float inv = 1.f / sum;
    float4 b0 = ((const float4*)bias)[2 * l16];
    float4 b1 = ((const float4*)bias)[2 * l16 + 1];
    uint4 o;
    o.x = pack_bf16x2(a01.x * inv + b0.x, a01.y * inv + b0.y);
    o.y = pack_bf16x2(a23.x * inv + b0.z, a23.y * inv + b0.w);
    o.z = pack_bf16x2(a45.x * inv + b1.x, a45.y * inv + b1.y);
    o.w = pack_bf16x2(a67.x * inv + b1.z, a67.y * inv + b1.w);
    ((uint4*)(hagg + (size_t)d * 64))[l16] = o;
}

// ---------------------------------------------------------------------------
// BN column sums / sums-of-squares over bf16 [N,128]
// ---------------------------------------------------------------------------
__global__ void k_bnstats(const uint* __restrict__ hagg, int N,
                          float* __restrict__ sums, float* __restrict__ sumsq) {
    int t = threadIdx.x;
    int cg = t & 31, rs = t >> 5;
    float4 s = make_float4(0.f, 0.f, 0.f, 0.f), q = make_float4(0.f, 0.f, 0.f, 0.f);
    for (int n = blockIdx.x * 8 + rs; n < N; n += gridDim.x * 8) {
        uint2 u = ((const uint2*)(hagg + (size_t)n * 64))[cg];
        float v0 = bflo(u.x), v1 = bfhi(u.x), v2 = bflo(u.y), v3 = bfhi(u.y);
        s.x += v0; s.y += v1; s.z += v2; s.w += v3;
        q.x += v0 * v0; q.y += v1 * v1; q.z += v2 * v2; q.w += v3 * v3;
    }
    __shared__ float4 ls[256], lq[256];
    ls[t] = s; lq[t] = q;
    __syncthreads();
    if (t < 32) {
        float4 S = ls[t], Q = lq[t];
        for (int r = 1; r < 8; r++) {
            float4 a = ls[t + r * 32], b = lq[t + r * 32];
            S.x += a.x; S.y += a.y; S.z += a.z; S.w += a.w;
            Q.x += b.x; Q.y += b.y; Q.z += b.z; Q.w += b.w;
        }
        atomicAdd(&sums[t * 4 + 0], S.x);
        atomicAdd(&sums[t * 4 + 1], S.y);
        atomicAdd(&sums[t * 4 + 2], S.z);
        atomicAdd(&sums[t * 4 + 3], S.w);
        atomicAdd(&sumsq[t * 4 + 0], Q.x);
        atomicAdd(&sumsq[t * 4 + 1], Q.y);
        atomicAdd(&sumsq[t * 4 + 2], Q.z);
        atomicAdd(&sumsq[t * 4 + 3], Q.w);
    }
}

// ---------------------------------------------------------------------------
// Per LUT node: BN + ReLU + MLP 128->32 (leaky 0.01) -> 1
// ---------------------------------------------------------------------------
__global__ void k_mlp(const uint* __restrict__ hagg, const int* __restrict__ lut,
                      const float* __restrict__ sums, const float* __restrict__ sumsq,
                      const float* __restrict__ gamma, const float* __restrict__ beta,
                      const float* __restrict__ W1, const float* __restrict__ b1,
                      const float* __restrict__ W2, const float* __restrict__ b2,
                      float* __restrict__ out, int N, int nlut) {
    int blk = blockIdx.x;
    if (blk >= nlut) return;
    int node = lut[blk];
    int lane = threadIdx.x;  // 64
    __shared__ float v[128];
    float invN = 1.f / (float)N;
    uint u = hagg[(size_t)node * 64 + lane];
    int c0 = 2 * lane, c1 = 2 * lane + 1;
    {
        float mean = sums[c0] * invN;
        float var = sumsq[c0] * invN - mean * mean;
        float val = (bflo(u) - mean) / sqrtf(var + 1e-5f) * gamma[c0] + beta[c0];
        v[c0] = fmaxf(val, 0.f);
        mean = sums[c1] * invN;
        var = sumsq[c1] * invN - mean * mean;
        val = (bfhi(u) - mean) / sqrtf(var + 1e-5f) * gamma[c1] + beta[c1];
        v[c1] = fmaxf(val, 0.f);
    }
    __syncthreads();
    float r = 0.f;
    if (lane < 32) {
        float z = b1[lane];
        for (int c = 0; c < 128; c++) z += v[c] * W1[c * 32 + lane];
        z = z > 0.f ? z : 0.01f * z;
        r = z * W2[lane];
    }
#pragma unroll
    for (int off = 16; off >= 1; off >>= 1) r += __shfl_xor(r, off);
    if (lane == 0) out[blk] = r + b2[0];
}

// ---------------------------------------------------------------------------
extern "C" void kernel_launch(void* const* d_in, const int* in_sizes, int n_in,
                              void* d_out, int out_size, void* d_ws, size_t ws_size,
                              hipStream_t stream) {
    const float* x     = (const float*)d_in[0];
    const int*   edges = (const int*)d_in[1];
    const int*   lut   = (const int*)d_in[2];
    const float* W_lin = (const float*)d_in[3];
    const float* att_s = (const float*)d_in[4];
    const float* att_d = (const float*)d_in[5];
    const float* bias  = (const float*)d_in[6];
    const float* gamma = (const float*)d_in[7];
    const float* beta  = (const float*)d_in[8];
    const float* W1    = (const float*)d_in[9];
    const float* b1    = (const float*)d_in[10];
    const float* W2    = (const float*)d_in[11];
    const float* b2    = (const float*)d_in[12];

    int N = in_sizes[0] / 16;
    int E = in_sizes[1] / 2;
    int nlut = in_sizes[2];
    int B = (N + 255) >> BSHIFT;   // 391 for N=100000

    const int* esrc = edges;
    const int* edst = edges + E;

    char* ws = (char*)d_ws;
    size_t off = 0;
    auto alloc = [&](size_t bytes) -> void* {
        void* p = ws + off;
        off += (bytes + 255) & ~(size_t)255;
        return p;
    };
    uint*  h       = (uint*)alloc((size_t)N * 64 * 4);          // bf16x2 [N,128]
    uint*  hagg    = (uint*)alloc((size_t)N * 64 * 4);          // bf16x2 [N,128]
    float* a_src   = (float*)alloc((size_t)N * 4 * 4);
    float* a_dst   = (float*)alloc((size_t)N * 4 * 4);
    int*   offsets = (int*)alloc((size_t)N * 4);
    int*   degs    = (int*)alloc((size_t)N * 4);
    int*   sorted  = (int*)alloc((size_t)B * SORT_CAP * 4);
    uint2* wsorted = (uint2*)alloc((size_t)B * SORT_CAP * 8);   // fp16x4 weights
    uint*  pairs   = (uint*)alloc((size_t)B * SORT_CAP * 4);
    int*   cursor  = (int*)alloc((size_t)NBUCK * 4);
    float* sums    = (float*)alloc(128 * 4);
    float* sumsq   = (float*)alloc(128 * 4);

    k_linear<<<(N + 3) / 4, 256, 0, stream>>>(x, W_lin, att_s, att_d, h, a_src, a_dst, N,
                                              cursor, sums, sumsq);
    kb_scatter<<<(E + TILE - 1) / TILE, SCAT_T, 0, stream>>>(esrc, edst, E, cursor, pairs);
    kb_sort<<<B, SORT_T, 0, stream>>>(pairs, cursor, a_src, a_dst, N,
                                      sorted, wsorted, offsets, degs);
    k_gat<<<(N + 15) / 16, 256, 0, stream>>>(offsets, degs, sorted, wsorted, h,
                                             a_src, a_dst, bias, hagg, N);
    k_bnstats<<<256, 256, 0, stream>>>(hagg, N, sums, sumsq);
    k_mlp<<<nlut, 64, 0, stream>>>(hagg, lut, sums, sumsq, gamma, beta, W1, b1, W2, b2,
                                   (float*)d_out, N, nlut);
}

// Round 16
// 239.126 us; speedup vs baseline: 1.1662x; 1.1639x over previous
//
#include <hip/hip_runtime.h>
#include <hip/hip_fp16.h>
#include <cstdint>
#include <cstring>

typedef unsigned int uint;

#define BSHIFT 8          // 256 nodes per bucket
#define NBUCK 512         // max buckets (N up to 131072)
#define TILE 4096         // kb_scatter tile
#define SCAT_T 512
#define SORT_T 512
#define SORT_CAP 5120     // per-bucket capacity (mean ~4092, +16 sigma)

__device__ __forceinline__ float leaky02(float x) { return x > 0.f ? x : 0.2f * x; }
__device__ __forceinline__ float bflo(uint u) { return __uint_as_float(u << 16); }
__device__ __forceinline__ float bfhi(uint u) { return __uint_as_float(u & 0xffff0000u); }

__device__ __forceinline__ uint pack_bf16x2(float a, float b) {
    uint ua = __float_as_uint(a), ub = __float_as_uint(b);
    ua += 0x7fffu + ((ua >> 16) & 1u);
    ub += 0x7fffu + ((ub >> 16) & 1u);
    return (ua >> 16) | (ub & 0xffff0000u);
}

__device__ __forceinline__ uint packh2(float a, float b) {
    __half ha = __float2half_rn(a), hb = __float2half_rn(b);
    unsigned short ua, ub;
    memcpy(&ua, &ha, 2);
    memcpy(&ub, &hb, 2);
    return (uint)ua | ((uint)ub << 16);
}

// ---------------------------------------------------------------------------
// Kernel A: h = x @ W_lin (bf16x2), a_src/a_dst per head.
// ILP-restructured: W (16xfloat2) in registers, x tile (32 nodes) staged in
// LDS, inner reads are same-address LDS broadcasts. Each wave owns 8 nodes
// (independent FMA chains). Block 0 zero-inits cursor/sums/sumsq.
// ---------------------------------------------------------------------------
__global__ void k_linear(const float* __restrict__ x, const float* __restrict__ W,
                         const float* __restrict__ att_s, const float* __restrict__ att_d,
                         uint* __restrict__ h, float* __restrict__ a_src,
                         float* __restrict__ a_dst, int N,
                         int* __restrict__ cursor, float* __restrict__ sums,
                         float* __restrict__ sumsq) {
    int tid = threadIdx.x;  // 256
    if (blockIdx.x == 0) {
        cursor[tid] = 0;
        cursor[tid + 256] = 0;
        if (tid < 128) { sums[tid] = 0.f; sumsq[tid] = 0.f; }
    }
    __shared__ float sx[32][16];
    int j = tid & 63;       // channel pair 0..63 (channels 2j, 2j+1)
    int sub = tid >> 6;     // wave id 0..3 -> node subgroup
    int head = j >> 4;
    int n0 = blockIdx.x * 32;

    // W into registers (one-time, coalesced; 32 VGPRs)
    float2 wreg[16];
#pragma unroll
    for (int k = 0; k < 16; k++) wreg[k] = ((const float2*)(W + k * 128))[j];
    float2 as = ((const float2*)att_s)[j];
    float2 ad = ((const float2*)att_d)[j];

    // stage x tile: 32 nodes x 16 floats = 128 float4
    if (tid < 128) {
        int row = tid >> 2;
        if (n0 + row < N)
            ((float4*)sx)[tid] = ((const float4*)(x + (size_t)n0 * 16))[tid];
    }
    __syncthreads();

#pragma unroll
    for (int i = 0; i < 8; i++) {
        int loc = sub + i * 4;
        int n = n0 + loc;
        if (n >= N) break;
        float acc0 = 0.f, acc1 = 0.f;
#pragma unroll
        for (int k = 0; k < 16; k++) {
            float xk = sx[loc][k];   // LDS broadcast (same addr across wave)
            acc0 += xk * wreg[k].x;
            acc1 += xk * wreg[k].y;
        }
        h[(size_t)n * 64 + j] = pack_bf16x2(acc0, acc1);
        float ps = acc0 * as.x + acc1 * as.y;
        float pd = acc0 * ad.x + acc1 * ad.y;
#pragma unroll
        for (int off = 1; off <= 8; off <<= 1) {
            ps += __shfl_xor(ps, off);
            pd += __shfl_xor(pd, off);
        }
        if ((j & 15) == 0) {
            a_src[n * 4 + head] = ps;
            a_dst[n * 4 + head] = pd;
        }
    }
}

// ---------------------------------------------------------------------------
// Scatter into capacity buckets: bucket b owns pairs[b*SORT_CAP ...].
// LDS-staged for dense bucket-contiguous writes. code = (src<<8)|(dst&255).
// ---------------------------------------------------------------------------
__global__ void kb_scatter(const int* __restrict__ src, const int* __restrict__ dst, int E,
                           int* __restrict__ cursor, uint* __restrict__ pairs) {
    __shared__ int tileCnt[NBUCK], tileCnt2[NBUCK], tileOff[NBUCK], gbase[NBUCK];
    __shared__ int sA[NBUCK], sB[NBUCK];
    __shared__ uint lp[TILE];
    __shared__ unsigned short lb[TILE];
    int tid = threadIdx.x;  // 512
    int t0 = blockIdx.x * TILE;
    tileCnt[tid] = 0;
    tileCnt2[tid] = 0;
    __syncthreads();
    int dreg[8], sreg[8];
#pragma unroll
    for (int j = 0; j < 8; j++) {
        int idx = t0 + j * SCAT_T + tid;
        if (idx < E) {
            dreg[j] = dst[idx];
            sreg[j] = src[idx];
            atomicAdd(&tileCnt[dreg[j] >> BSHIFT], 1);
        } else dreg[j] = -1;
    }
    __syncthreads();
    int* a = sA; int* b = sB;
    a[tid] = tileCnt[tid];
    __syncthreads();
    for (int off = 1; off < NBUCK; off <<= 1) {
        b[tid] = a[tid] + (tid >= off ? a[tid - off] : 0);
        __syncthreads();
        int* t = a; a = b; b = t;
    }
    tileOff[tid] = a[tid] - tileCnt[tid];
    if (tileCnt[tid] > 0) gbase[tid] = atomicAdd(&cursor[tid], tileCnt[tid]);
    __syncthreads();
#pragma unroll
    for (int j = 0; j < 8; j++) {
        if (dreg[j] >= 0) {
            int bk = dreg[j] >> BSHIFT;
            int r = atomicAdd(&tileCnt2[bk], 1);
            int pos = tileOff[bk] + r;
            lp[pos] = ((uint)sreg[j] << BSHIFT) | (uint)(dreg[j] & 255);
            lb[pos] = (unsigned short)bk;
        }
    }
    __syncthreads();
    int tot = min(TILE, E - t0);
    for (int k = tid; k < tot; k += SCAT_T) {
        int bk = lb[k];
        int lpos = gbase[bk] + (k - tileOff[bk]);
        if (lpos < SORT_CAP)
            pairs[(size_t)bk * SORT_CAP + lpos] = lp[k];
    }
}

// ---------------------------------------------------------------------------
// Per-bucket counting sort + per-edge weight precompute.
// Emits sorted[] (src) and wsorted[] (fp16x4 weights), both coalesced.
// a_dst slice staged in LDS.
// ---------------------------------------------------------------------------
__global__ void kb_sort(const uint* __restrict__ pairs, const int* __restrict__ cursor,
                        const float* __restrict__ a_src, const float* __restrict__ a_dst,
                        int N,
                        int* __restrict__ sorted, uint2* __restrict__ wsorted,
                        int* __restrict__ offsets, int* __restrict__ degs) {
    __shared__ int cnt[256], off0[256], sA[256], sB[256];
    __shared__ uint lcode[SORT_CAP];
    __shared__ float4 sad[256];
    int tid = threadIdx.x;  // 512
    int b = blockIdx.x;
    int n0 = b << BSHIFT;
    int nn = min(256, N - n0);
    int ebase = b * SORT_CAP;
    int ecnt = cursor[b];
    if (ecnt > SORT_CAP) ecnt = SORT_CAP;
    if (tid < 256) cnt[tid] = 0;
    if (tid < nn) sad[tid] = ((const float4*)a_dst)[n0 + tid];
    __syncthreads();
    for (int k = tid; k < ecnt; k += SORT_T)
        atomicAdd(&cnt[pairs[ebase + k] & 255], 1);
    __syncthreads();
    int v = 0;
    int* a = sA; int* bb = sB;
    if (tid < 256) { v = cnt[tid]; a[tid] = v; }
    __syncthreads();
    for (int off = 1; off < 256; off <<= 1) {
        if (tid < 256) bb[tid] = a[tid] + (tid >= off ? a[tid - off] : 0);
        __syncthreads();
        int* t = a; a = bb; bb = t;
    }
    if (tid < 256) off0[tid] = a[tid] - v;
    __syncthreads();
    if (tid < 256) cnt[tid] = 0;
    __syncthreads();
    for (int k = tid; k < ecnt; k += SORT_T) {
        uint p = pairs[ebase + k];
        int ln = p & 255;
        int r = atomicAdd(&cnt[ln], 1);
        lcode[off0[ln] + r] = p;
    }
    __syncthreads();
    // pass 2: in-order, fully coalesced emit
    for (int k = tid; k < ecnt; k += SORT_T) {
        uint p = lcode[k];
        int src = (int)(p >> BSHIFT);
        int ln = p & 255;
        sorted[ebase + k] = src;
        float4 as = ((const float4*)a_src)[src];
        float4 ad = sad[ln];
        float w0 = __expf(leaky02(as.x + ad.x));
        float w1 = __expf(leaky02(as.y + ad.y));
        float w2 = __expf(leaky02(as.z + ad.z));
        float w3 = __expf(leaky02(as.w + ad.w));
        wsorted[ebase + k] = make_uint2(packh2(w0, w1), packh2(w2, w3));
    }
    if (tid < nn) {
        offsets[n0 + tid] = ebase + off0[tid];
        degs[n0 + tid] = v;
    }
}

// ---------------------------------------------------------------------------
// GAT aggregation: 4 nodes per wave, 16 lanes per node (8 ch/lane, uint4).
// Unroll x4: 4 edges in flight per node group (16 outstanding gathers/wave).
// No cross-lane merges; weight-sum accumulated redundantly per lane.
// ---------------------------------------------------------------------------
__global__ void k_gat(const int* __restrict__ offsets, const int* __restrict__ degs,
                      const int* __restrict__ sorted, const uint2* __restrict__ wsorted,
                      const uint* __restrict__ h, const float* __restrict__ a_src,
                      const float* __restrict__ a_dst, const float* __restrict__ bias,
                      uint* __restrict__ hagg, int N) {
    int nb = gridDim.x;
    int g = nb >> 3;
    int bi = blockIdx.x;
    int blk = (bi < (g << 3)) ? ((bi & 7) * g + (bi >> 3)) : bi;
    int lane = threadIdx.x & 63;
    int wid = threadIdx.x >> 6;
    int q = lane >> 4;      // node group within wave
    int l16 = lane & 15;    // channel group: 8 channels (uint4)
    int head = l16 >> 2;
    int d = blk * 16 + wid * 4 + q;
    if (d >= N) return;
    int base = offsets[d];
    int deg = degs[d];

    const int* sp = sorted + base;
    const __half* wp = (const __half*)(wsorted + base) + head;

    // self loop
    float w = __expf(leaky02(a_src[d * 4 + head] + a_dst[d * 4 + head]));
    uint4 u = ((const uint4*)(h + (size_t)d * 64))[l16];
    float sum = w;
    float2 a01 = make_float2(w * bflo(u.x), w * bfhi(u.x));
    float2 a23 = make_float2(w * bflo(u.y), w * bfhi(u.y));
    float2 a45 = make_float2(w * bflo(u.z), w * bfhi(u.z));
    float2 a67 = make_float2(w * bflo(u.w), w * bfhi(u.w));

    int i = 0;
    for (; i + 3 < deg; i += 4) {
        int s0 = sp[i];
        int s1 = sp[i + 1];
        int s2 = sp[i + 2];
        int s3 = sp[i + 3];
        float w0 = __half2float(wp[i * 4]);
        float w1 = __half2float(wp[(i + 1) * 4]);
        float w2 = __half2float(wp[(i + 2) * 4]);
        float w3 = __half2float(wp[(i + 3) * 4]);
        uint4 u0 = ((const uint4*)(h + (size_t)s0 * 64))[l16];
        uint4 u1 = ((const uint4*)(h + (size_t)s1 * 64))[l16];
        uint4 u2 = ((const uint4*)(h + (size_t)s2 * 64))[l16];
        uint4 u3 = ((const uint4*)(h + (size_t)s3 * 64))[l16];
        sum += (w0 + w1) + (w2 + w3);
        float2 w02 = {w0, w0}, w12 = {w1, w1}, w22 = {w2, w2}, w32 = {w3, w3};
        a01 += make_float2(bflo(u0.x), bfhi(u0.x)) * w02
             + make_float2(bflo(u1.x), bfhi(u1.x)) * w12
             + make_float2(bflo(u2.x), bfhi(u2.x)) * w22
             + make_float2(bflo(u3.x), bfhi(u3.x)) * w32;
        a23 += make_float2(bflo(u0.y), bfhi(u0.y)) * w02
             + make_float2(bflo(u1.y), bfhi(u1.y)) * w12
             + make_float2(bflo(u2.y), bfhi(u2.y)) * w22
             + make_float2(bflo(u3.y), bfhi(u3.y)) * w32;
        a45 += make_float2(bflo(u0.z), bfhi(u0.z)) * w02
             + make_float2(bflo(u1.z), bfhi(u1.z)) * w12
             + make_float2(bflo(u2.z), bfhi(u2.z)) * w22
             + make_float2(bflo(u3.z), bfhi(u3.z)) * w32;
        a67 += make_float2(bflo(u0.w), bfhi(u0.w)) * w02
             + make_float2(bflo(u1.w), bfhi(u1.w)) * w12
             + make_float2(bflo(u2.w), bfhi(u2.w)) * w22
             + make_float2(bflo(u3.w), bfhi(u3.w)) * w32;
    }
    for (; i < deg; i++) {
        int s0 = sp[i];
        float w0 = __half2float(wp[i * 4]);
        uint4 u0 = ((const uint4*)(h + (size_t)s0 * 64))[l16];
        sum += w0;
        float2 w02 = {w0, w0};
        a01 += make_float2(bflo(u0.x), bfhi(u0.x)) * w02;
        a23 += make_float2(bflo(u0.y), bfhi(u0.y)) * w02;
        a45 += make_float2(bflo(u0.z), bfhi(u0.z)) * w02;
        a67 += make_float2(bflo(u0.w), bfhi(u0.w)) * w02;
    }
    float inv = 1.f / sum;
    float4 b0 = ((const float4*)bias)[2 * l16];
    float4 b1 = ((const float4*)bias)[2 * l16 + 1];
    uint4 o;
    o.x = pack_bf16x2(a01.x * inv + b0.x, a01.y * inv + b0.y);
    o.y = pack_bf16x2(a23.x * inv + b0.z, a23.y * inv + b0.w);
    o.z = pack_bf16x2(a45.x * inv + b1.x, a45.y * inv + b1.y);
    o.w = pack_bf16x2(a67.x * inv + b1.z, a67.y * inv + b1.w);
    ((uint4*)(hagg + (size_t)d * 64))[l16] = o;
}

// ---------------------------------------------------------------------------
// BN column sums / sums-of-squares over bf16 [N,128]
// ---------------------------------------------------------------------------
__global__ void k_bnstats(const uint* __restrict__ hagg, int N,
                          float* __restrict__ sums, float* __restrict__ sumsq) {
    int t = threadIdx.x;
    int cg = t & 31, rs = t >> 5;
    float4 s = make_float4(0.f, 0.f, 0.f, 0.f), q = make_float4(0.f, 0.f, 0.f, 0.f);
    for (int n = blockIdx.x * 8 + rs; n < N; n += gridDim.x * 8) {
        uint2 u = ((const uint2*)(hagg + (size_t)n * 64))[cg];
        float v0 = bflo(u.x), v1 = bfhi(u.x), v2 = bflo(u.y), v3 = bfhi(u.y);
        s.x += v0; s.y += v1; s.z += v2; s.w += v3;
        q.x += v0 * v0; q.y += v1 * v1; q.z += v2 * v2; q.w += v3 * v3;
    }
    __shared__ float4 ls[256], lq[256];
    ls[t] = s; lq[t] = q;
    __syncthreads();
    if (t < 32) {
        float4 S = ls[t], Q = lq[t];
        for (int r = 1; r < 8; r++) {
            float4 a = ls[t + r * 32], b = lq[t + r * 32];
            S.x += a.x; S.y += a.y; S.z += a.z; S.w += a.w;
            Q.x += b.x; Q.y += b.y; Q.z += b.z; Q.w += b.w;
        }
        atomicAdd(&sums[t * 4 + 0], S.x);
        atomicAdd(&sums[t * 4 + 1], S.y);
        atomicAdd(&sums[t * 4 + 2], S.z);
        atomicAdd(&sums[t * 4 + 3], S.w);
        atomicAdd(&sumsq[t * 4 + 0], Q.x);
        atomicAdd(&sumsq[t * 4 + 1], Q.y);
        atomicAdd(&sumsq[t * 4 + 2], Q.z);
        atomicAdd(&sumsq[t * 4 + 3], Q.w);
    }
}

// ---------------------------------------------------------------------------
// Per LUT node: BN + ReLU + MLP 128->32 (leaky 0.01) -> 1
// ---------------------------------------------------------------------------
__global__ void k_mlp(const uint* __restrict__ hagg, const int* __restrict__ lut,
                      const float* __restrict__ sums, const float* __restrict__ sumsq,
                      const float* __restrict__ gamma, const float* __restrict__ beta,
                      const float* __restrict__ W1, const float* __restrict__ b1,
                      const float* __restrict__ W2, const float* __restrict__ b2,
                      float* __restrict__ out, int N, int nlut) {
    int blk = blockIdx.x;
    if (blk >= nlut) return;
    int node = lut[blk];
    int lane = threadIdx.x;  // 64
    __shared__ float v[128];
    float invN = 1.f / (float)N;
    uint u = hagg[(size_t)node * 64 + lane];
    int c0 = 2 * lane, c1 = 2 * lane + 1;
    {
        float mean = sums[c0] * invN;
        float var = sumsq[c0] * invN - mean * mean;
        float val = (bflo(u) - mean) / sqrtf(var + 1e-5f) * gamma[c0] + beta[c0];
        v[c0] = fmaxf(val, 0.f);
        mean = sums[c1] * invN;
        var = sumsq[c1] * invN - mean * mean;
        val = (bfhi(u) - mean) / sqrtf(var + 1e-5f) * gamma[c1] + beta[c1];
        v[c1] = fmaxf(val, 0.f);
    }
    __syncthreads();
    float r = 0.f;
    if (lane < 32) {
        float z = b1[lane];
        for (int c = 0; c < 128; c++) z += v[c] * W1[c * 32 + lane];
        z = z > 0.f ? z : 0.01f * z;
        r = z * W2[lane];
    }
#pragma unroll
    for (int off = 16; off >= 1; off >>= 1) r += __shfl_xor(r, off);
    if (lane == 0) out[blk] = r + b2[0];
}

// ---------------------------------------------------------------------------
extern "C" void kernel_launch(void* const* d_in, const int* in_sizes, int n_in,
                              void* d_out, int out_size, void* d_ws, size_t ws_size,
                              hipStream_t stream) {
    const float* x     = (const float*)d_in[0];
    const int*   edges = (const int*)d_in[1];
    const int*   lut   = (const int*)d_in[2];
    const float* W_lin = (const float*)d_in[3];
    const float* att_s = (const float*)d_in[4];
    const float* att_d = (const float*)d_in[5];
    const float* bias  = (const float*)d_in[6];
    const float* gamma = (const float*)d_in[7];
    const float* beta  = (const float*)d_in[8];
    const float* W1    = (const float*)d_in[9];
    const float* b1    = (const float*)d_in[10];
    const float* W2    = (const float*)d_in[11];
    const float* b2    = (const float*)d_in[12];

    int N = in_sizes[0] / 16;
    int E = in_sizes[1] / 2;
    int nlut = in_sizes[2];
    int B = (N + 255) >> BSHIFT;   // 391 for N=100000

    const int* esrc = edges;
    const int* edst = edges + E;

    char* ws = (char*)d_ws;
    size_t off = 0;
    auto alloc = [&](size_t bytes) -> void* {
        void* p = ws + off;
        off += (bytes + 255) & ~(size_t)255;
        return p;
    };
    uint*  h       = (uint*)alloc((size_t)N * 64 * 4);          // bf16x2 [N,128]
    uint*  hagg    = (uint*)alloc((size_t)N * 64 * 4);          // bf16x2 [N,128]
    float* a_src   = (float*)alloc((size_t)N * 4 * 4);
    float* a_dst   = (float*)alloc((size_t)N * 4 * 4);
    int*   offsets = (int*)alloc((size_t)N * 4);
    int*   degs    = (int*)alloc((size_t)N * 4);
    int*   sorted  = (int*)alloc((size_t)B * SORT_CAP * 4);
    uint2* wsorted = (uint2*)alloc((size_t)B * SORT_CAP * 8);   // fp16x4 weights
    uint*  pairs   = (uint*)alloc((size_t)B * SORT_CAP * 4);
    int*   cursor  = (int*)alloc((size_t)NBUCK * 4);
    float* sums    = (float*)alloc(128 * 4);
    float* sumsq   = (float*)alloc(128 * 4);

    k_linear<<<(N + 31) / 32, 256, 0, stream>>>(x, W_lin, att_s, att_d, h, a_src, a_dst, N,
                                                cursor, sums, sumsq);
    kb_scatter<<<(E + TILE - 1) / TILE, SCAT_T, 0, stream>>>(esrc, edst, E, cursor, pairs);
    kb_sort<<<B, SORT_T, 0, stream>>>(pairs, cursor, a_src, a_dst, N,
                                      sorted, wsorted, offsets, degs);
    k_gat<<<(N + 15) / 16, 256, 0, stream>>>(offsets, degs, sorted, wsorted, h,
                                             a_src, a_dst, bias, hagg, N);
    k_bnstats<<<256, 256, 0, stream>>>(hagg, N, sums, sumsq);
    k_mlp<<<nlut, 64, 0, stream>>>(hagg, lut, sums, sumsq, gamma, beta, W1, b1, W2, b2,
                                   (float*)d_out, N, nlut);
}

// Round 17
// 236.290 us; speedup vs baseline: 1.1802x; 1.0120x over previous
//
#include <hip/hip_runtime.h>
#include <hip/hip_fp16.h>
#include <cstdint>
#include <cstring>

typedef unsigned int uint;

#define BSHIFT 8          // 256 nodes per bucket
#define NBUCK 512         // max buckets (N up to 131072)
#define TILE 4096         // kb_scatter tile
#define SCAT_T 512
#define SORT_T 512
#define SORT_CAP 5120     // per-bucket capacity (mean ~4092, +16 sigma)

__device__ __forceinline__ float leaky02(float x) { return x > 0.f ? x : 0.2f * x; }
__device__ __forceinline__ float bflo(uint u) { return __uint_as_float(u << 16); }
__device__ __forceinline__ float bfhi(uint u) { return __uint_as_float(u & 0xffff0000u); }

__device__ __forceinline__ uint pack_bf16x2(float a, float b) {
    uint ua = __float_as_uint(a), ub = __float_as_uint(b);
    ua += 0x7fffu + ((ua >> 16) & 1u);
    ub += 0x7fffu + ((ub >> 16) & 1u);
    return (ua >> 16) | (ub & 0xffff0000u);
}

__device__ __forceinline__ uint packh2(float a, float b) {
    __half ha = __float2half_rn(a), hb = __float2half_rn(b);
    unsigned short ua, ub;
    memcpy(&ua, &ha, 2);
    memcpy(&ub, &hb, 2);
    return (uint)ua | ((uint)ub << 16);
}

// ---------------------------------------------------------------------------
// k_prep (1 block, 128 threads): zero-init cursor/sums/sumsq; precompute
// Ws[k][h] = sum_c W[k][128h+c]*att_s[h][c] and Wd likewise (16x4 each).
// ---------------------------------------------------------------------------
__global__ void k_prep(const float* __restrict__ W, const float* __restrict__ att_s,
                       const float* __restrict__ att_d, float* __restrict__ WsWd,
                       int* __restrict__ cursor, float* __restrict__ sums,
                       float* __restrict__ sumsq) {
    int t = threadIdx.x;  // 128
    cursor[t] = 0; cursor[t + 128] = 0; cursor[t + 256] = 0; cursor[t + 384] = 0;
    sums[t] = 0.f; sumsq[t] = 0.f;
    if (t < 64) {
        int k = t >> 2, hh = t & 3;
        float s1 = 0.f, s2 = 0.f;
        for (int c = 0; c < 32; c++) {
            float wv = W[k * 128 + hh * 32 + c];
            s1 += wv * att_s[hh * 32 + c];
            s2 += wv * att_d[hh * 32 + c];
        }
        WsWd[t] = s1;        // Ws flat [k*4+h]
        WsWd[64 + t] = s2;   // Wd flat [k*4+h]
    }
}

// ---------------------------------------------------------------------------
// Kernel A: h = x @ W_lin (bf16x2); a_src/a_dst via precomputed 16x4 Ws/Wd
// (no cross-lane reductions). W in registers, x tile (32 nodes) in LDS.
// ---------------------------------------------------------------------------
__global__ void k_linear(const float* __restrict__ x, const float* __restrict__ W,
                         const float* __restrict__ WsWd,
                         uint* __restrict__ h, float* __restrict__ a_src,
                         float* __restrict__ a_dst, int N) {
    int tid = threadIdx.x;  // 256
    __shared__ float sx[32][16];
    __shared__ float sWs[64], sWd[64];
    int j = tid & 63;       // channel pair
    int sub = tid >> 6;     // wave id -> node subgroup
    int n0 = blockIdx.x * 32;

    float2 wreg[16];
#pragma unroll
    for (int k = 0; k < 16; k++) wreg[k] = ((const float2*)(W + k * 128))[j];

    if (tid < 128) {
        int row = tid >> 2;
        if (n0 + row < N)
            ((float4*)sx)[tid] = ((const float4*)(x + (size_t)n0 * 16))[tid];
    } else if (tid < 192) {
        sWs[tid - 128] = WsWd[tid - 128];
    } else {
        sWd[tid - 192] = WsWd[64 + (tid - 192)];
    }
    __syncthreads();

#pragma unroll
    for (int i = 0; i < 8; i++) {
        int loc = sub + i * 4;
        int n = n0 + loc;
        if (n >= N) break;
        float acc0 = 0.f, acc1 = 0.f;
#pragma unroll
        for (int k = 0; k < 16; k++) {
            float xk = sx[loc][k];
            acc0 += xk * wreg[k].x;
            acc1 += xk * wreg[k].y;
        }
        h[(size_t)n * 64 + j] = pack_bf16x2(acc0, acc1);
    }

    // a_src / a_dst: thread t -> (node tid>>3, head (tid>>1)&3, sd tid&1)
    int loc2 = tid >> 3, hh = (tid >> 1) & 3, sd = tid & 1;
    int n2 = n0 + loc2;
    if (n2 < N) {
        const float* Wm = sd ? sWd : sWs;
        float acc = 0.f;
#pragma unroll
        for (int k = 0; k < 16; k++) acc += sx[loc2][k] * Wm[k * 4 + hh];
        if (sd) a_dst[n2 * 4 + hh] = acc;
        else    a_src[n2 * 4 + hh] = acc;
    }
}

// ---------------------------------------------------------------------------
// Scatter into capacity buckets: bucket b owns pairs[b*SORT_CAP ...].
// LDS-staged dense writes; wave-shfl scan (2 barriers instead of ~18).
// code = (src<<8)|(dst&255).
// ---------------------------------------------------------------------------
__global__ void kb_scatter(const int* __restrict__ src, const int* __restrict__ dst, int E,
                           int* __restrict__ cursor, uint* __restrict__ pairs) {
    __shared__ int tileCnt[NBUCK], tileCnt2[NBUCK], tileOff[NBUCK], gbase[NBUCK];
    __shared__ int wsum[8], wbase[8];
    __shared__ uint lp[TILE];
    __shared__ unsigned short lb[TILE];
    int tid = threadIdx.x;  // 512
    int l = tid & 63, w = tid >> 6;
    int t0 = blockIdx.x * TILE;
    tileCnt[tid] = 0;
    tileCnt2[tid] = 0;
    __syncthreads();
    int dreg[8], sreg[8];
#pragma unroll
    for (int j = 0; j < 8; j++) {
        int idx = t0 + j * SCAT_T + tid;
        if (idx < E) {
            dreg[j] = dst[idx];
            sreg[j] = src[idx];
            atomicAdd(&tileCnt[dreg[j] >> BSHIFT], 1);
        } else dreg[j] = -1;
    }
    __syncthreads();
    // wave-shfl exclusive scan over 512 entries
    int v = tileCnt[tid];
    int s = v;
#pragma unroll
    for (int off = 1; off < 64; off <<= 1) {
        int t = __shfl_up(s, off);
        if (l >= off) s += t;
    }
    if (l == 63) wsum[w] = s;
    __syncthreads();
    if (tid < 8) {
        int b = 0;
        for (int i = 0; i < tid; i++) b += wsum[i];
        wbase[tid] = b;
    }
    __syncthreads();
    int ex = s - v + wbase[w];
    tileOff[tid] = ex;
    if (v > 0) gbase[tid] = atomicAdd(&cursor[tid], v);
    __syncthreads();
#pragma unroll
    for (int j = 0; j < 8; j++) {
        if (dreg[j] >= 0) {
            int bk = dreg[j] >> BSHIFT;
            int r = atomicAdd(&tileCnt2[bk], 1);
            int pos = tileOff[bk] + r;
            lp[pos] = ((uint)sreg[j] << BSHIFT) | (uint)(dreg[j] & 255);
            lb[pos] = (unsigned short)bk;
        }
    }
    __syncthreads();
    int tot = min(TILE, E - t0);
    for (int k = tid; k < tot; k += SCAT_T) {
        int bk = lb[k];
        int lpos = gbase[bk] + (k - tileOff[bk]);
        if (lpos < SORT_CAP)
            pairs[(size_t)bk * SORT_CAP + lpos] = lp[k];
    }
}

// ---------------------------------------------------------------------------
// Per-bucket counting sort + per-edge weight precompute.
// Wave-shfl scan; emits sorted[] (src) and wsorted[] (fp16x4), coalesced.
// ---------------------------------------------------------------------------
__global__ void kb_sort(const uint* __restrict__ pairs, const int* __restrict__ cursor,
                        const float* __restrict__ a_src, const float* __restrict__ a_dst,
                        int N,
                        int* __restrict__ sorted, uint2* __restrict__ wsorted,
                        int* __restrict__ offsets, int* __restrict__ degs) {
    __shared__ int cnt[256], off0[256];
    __shared__ int wsum[4], wbase[4];
    __shared__ uint lcode[SORT_CAP];
    __shared__ float4 sad[256];
    int tid = threadIdx.x;  // 512
    int l = tid & 63, w = tid >> 6;
    int b = blockIdx.x;
    int n0 = b << BSHIFT;
    int nn = min(256, N - n0);
    int ebase = b * SORT_CAP;
    int ecnt = cursor[b];
    if (ecnt > SORT_CAP) ecnt = SORT_CAP;
    if (tid < 256) cnt[tid] = 0;
    if (tid < nn) sad[tid] = ((const float4*)a_dst)[n0 + tid];
    __syncthreads();
    for (int k = tid; k < ecnt; k += SORT_T)
        atomicAdd(&cnt[pairs[ebase + k] & 255], 1);
    __syncthreads();
    // wave-shfl exclusive scan over 256 entries (waves 0..3)
    int v = (tid < 256) ? cnt[tid] : 0;
    int s = v;
#pragma unroll
    for (int off = 1; off < 64; off <<= 1) {
        int t = __shfl_up(s, off);
        if (l >= off) s += t;
    }
    if (tid < 256 && l == 63) wsum[w] = s;
    __syncthreads();
    if (tid < 4) {
        int base = 0;
        for (int i = 0; i < tid; i++) base += wsum[i];
        wbase[tid] = base;
    }
    __syncthreads();
    if (tid < 256) off0[tid] = s - v + wbase[w];
    __syncthreads();
    if (tid < 256) cnt[tid] = 0;
    __syncthreads();
    for (int k = tid; k < ecnt; k += SORT_T) {
        uint p = pairs[ebase + k];
        int ln = p & 255;
        int r = atomicAdd(&cnt[ln], 1);
        lcode[off0[ln] + r] = p;
    }
    __syncthreads();
    // pass 2: in-order, fully coalesced emit
    for (int k = tid; k < ecnt; k += SORT_T) {
        uint p = lcode[k];
        int src = (int)(p >> BSHIFT);
        int ln = p & 255;
        sorted[ebase + k] = src;
        float4 as = ((const float4*)a_src)[src];
        float4 ad = sad[ln];
        float w0 = __expf(leaky02(as.x + ad.x));
        float w1 = __expf(leaky02(as.y + ad.y));
        float w2 = __expf(leaky02(as.z + ad.z));
        float w3 = __expf(leaky02(as.w + ad.w));
        wsorted[ebase + k] = make_uint2(packh2(w0, w1), packh2(w2, w3));
    }
    if (tid < nn) {
        offsets[n0 + tid] = ebase + off0[tid];
        degs[n0 + tid] = v;
    }
}

// ---------------------------------------------------------------------------
// GAT aggregation: 4 nodes per wave, 16 lanes per node (8 ch/lane, uint4).
// Unroll x4: 4 edges in flight per node group. No cross-lane merges.
// ---------------------------------------------------------------------------
__global__ void k_gat(const int* __restrict__ offsets, const int* __restrict__ degs,
                      const int* __restrict__ sorted, const uint2* __restrict__ wsorted,
                      const uint* __restrict__ h, const float* __restrict__ a_src,
                      const float* __restrict__ a_dst, const float* __restrict__ bias,
                      uint* __restrict__ hagg, int N) {
    int nb = gridDim.x;
    int g = nb >> 3;
    int bi = blockIdx.x;
    int blk = (bi < (g << 3)) ? ((bi & 7) * g + (bi >> 3)) : bi;
    int lane = threadIdx.x & 63;
    int wid = threadIdx.x >> 6;
    int q = lane >> 4;
    int l16 = lane & 15;
    int head = l16 >> 2;
    int d = blk * 16 + wid * 4 + q;
    if (d >= N) return;
    int base = offsets[d];
    int deg = degs[d];

    const int* sp = sorted + base;
    const __half* wp = (const __half*)(wsorted + base) + head;

    float w = __expf(leaky02(a_src[d * 4 + head] + a_dst[d * 4 + head]));
    uint4 u = ((const uint4*)(h + (size_t)d * 64))[l16];
    float sum = w;
    float2 a01 = make_float2(w * bflo(u.x), w * bfhi(u.x));
    float2 a23 = make_float2(w * bflo(u.y), w * bfhi(u.y));
    float2 a45 = make_float2(w * bflo(u.z), w * bfhi(u.z));
    float2 a67 = make_float2(w * bflo(u.w), w * bfhi(u.w));

    int i = 0;
    for (; i + 3 < deg; i += 4) {
        int s0 = sp[i];
        int s1 = sp[i + 1];
        int s2 = sp[i + 2];
        int s3 = sp[i + 3];
        float w0 = __half2float(wp[i * 4]);
        float w1 = __half2float(wp[(i + 1) * 4]);
        float w2 = __half2float(wp[(i + 2) * 4]);
        float w3 = __half2float(wp[(i + 3) * 4]);
        uint4 u0 = ((const uint4*)(h + (size_t)s0 * 64))[l16];
        uint4 u1 = ((const uint4*)(h + (size_t)s1 * 64))[l16];
        uint4 u2 = ((const uint4*)(h + (size_t)s2 * 64))[l16];
        uint4 u3 = ((const uint4*)(h + (size_t)s3 * 64))[l16];
        sum += (w0 + w1) + (w2 + w3);
        float2 w02 = {w0, w0}, w12 = {w1, w1}, w22 = {w2, w2}, w32 = {w3, w3};
        a01 += make_float2(bflo(u0.x), bfhi(u0.x)) * w02
             + make_float2(bflo(u1.x), bfhi(u1.x)) * w12
             + make_float2(bflo(u2.x), bfhi(u2.x)) * w22
             + make_float2(bflo(u3.x), bfhi(u3.x)) * w32;
        a23 += make_float2(bflo(u0.y), bfhi(u0.y)) * w02
             + make_float2(bflo(u1.y), bfhi(u1.y)) * w12
             + make_float2(bflo(u2.y), bfhi(u2.y)) * w22
             + make_float2(bflo(u3.y), bfhi(u3.y)) * w32;
        a45 += make_float2(bflo(u0.z), bfhi(u0.z)) * w02
             + make_float2(bflo(u1.z), bfhi(u1.z)) * w12
             + make_float2(bflo(u2.z), bfhi(u2.z)) * w22
             + make_float2(bflo(u3.z), bfhi(u3.z)) * w32;
        a67 += make_float2(bflo(u0.w), bfhi(u0.w)) * w02
             + make_float2(bflo(u1.w), bfhi(u1.w)) * w12
             + make_float2(bflo(u2.w), bfhi(u2.w)) * w22
             + make_float2(bflo(u3.w), bfhi(u3.w)) * w32;
    }
    for (; i < deg; i++) {
        int s0 = sp[i];
        float w0 = __half2float(wp[i * 4]);
        uint4 u0 = ((const uint4*)(h + (size_t)s0 * 64))[l16];
        sum += w0;
        float2 w02 = {w0, w0};
        a01 += make_float2(bflo(u0.x), bfhi(u0.x)) * w02;
        a23 += make_float2(bflo(u0.y), bfhi(u0.y)) * w02;
        a45 += make_float2(bflo(u0.z), bfhi(u0.z)) * w02;
        a67 += make_float2(bflo(u0.w), bfhi(u0.w)) * w02;
    }
    float inv = 1.f / sum;
    float4 b0 = ((const float4*)bias)[2 * l16];
    float4 b1 = ((const float4*)bias)[2 * l16 + 1];
    uint4 o;
    o.x = pack_bf16x2(a01.x * inv + b0.x, a01.y * inv + b0.y);
    o.y = pack_bf16x2(a23.x * inv + b0.z, a23.y * inv + b0.w);
    o.z = pack_bf16x2(a45.x * inv + b1.x, a45.y * inv + b1.y);
    o.w = pack_bf16x2(a67.x * inv + b1.z, a67.y * inv + b1.w);
    ((uint4*)(hagg + (size_t)d * 64))[l16] = o;
}

// ---------------------------------------------------------------------------
// BN column sums / sums-of-squares over bf16 [N,128]
// ---------------------------------------------------------------------------
__global__ void k_bnstats(const uint* __restrict__ hagg, int N,
                          float* __restrict__ sums, float* __restrict__ sumsq) {
    int t = threadIdx.x;
    int cg = t & 31, rs = t >> 5;
    float4 s = make_float4(0.f, 0.f, 0.f, 0.f), q = make_float4(0.f, 0.f, 0.f, 0.f);
    for (int n = blockIdx.x * 8 + rs; n < N; n += gridDim.x * 8) {
        uint2 u = ((const uint2*)(hagg + (size_t)n * 64))[cg];
        float v0 = bflo(u.x), v1 = bfhi(u.x), v2 = bflo(u.y), v3 = bfhi(u.y);
        s.x += v0; s.y += v1; s.z += v2; s.w += v3;
        q.x += v0 * v0; q.y += v1 * v1; q.z += v2 * v2; q.w += v3 * v3;
    }
    __shared__ float4 ls[256], lq[256];
    ls[t] = s; lq[t] = q;
    __syncthreads();
    if (t < 32) {
        float4 S = ls[t], Q = lq[t];
        for (int r = 1; r < 8; r++) {
            float4 a = ls[t + r * 32], b = lq[t + r * 32];
            S.x += a.x; S.y += a.y; S.z += a.z; S.w += a.w;
            Q.x += b.x; Q.y += b.y; Q.z += b.z; Q.w += b.w;
        }
        atomicAdd(&sums[t * 4 + 0], S.x);
        atomicAdd(&sums[t * 4 + 1], S.y);
        atomicAdd(&sums[t * 4 + 2], S.z);
        atomicAdd(&sums[t * 4 + 3], S.w);
        atomicAdd(&sumsq[t * 4 + 0], Q.x);
        atomicAdd(&sumsq[t * 4 + 1], Q.y);
        atomicAdd(&sumsq[t * 4 + 2], Q.z);
        atomicAdd(&sumsq[t * 4 + 3], Q.w);
    }
}

// ---------------------------------------------------------------------------
// Per LUT node: BN + ReLU + MLP 128->32 (leaky 0.01) -> 1
// ---------------------------------------------------------------------------
__global__ void k_mlp(const uint* __restrict__ hagg, const int* __restrict__ lut,
                      const float* __restrict__ sums, const float* __restrict__ sumsq,
                      const float* __restrict__ gamma, const float* __restrict__ beta,
                      const float* __restrict__ W1, const float* __restrict__ b1,
                      const float* __restrict__ W2, const float* __restrict__ b2,
                      float* __restrict__ out, int N, int nlut) {
    int blk = blockIdx.x;
    if (blk >= nlut) return;
    int node = lut[blk];
    int lane = threadIdx.x;  // 64
    __shared__ float v[128];
    float invN = 1.f / (float)N;
    uint u = hagg[(size_t)node * 64 + lane];
    int c0 = 2 * lane, c1 = 2 * lane + 1;
    {
        float mean = sums[c0] * invN;
        float var = sumsq[c0] * invN - mean * mean;
        float val = (bflo(u) - mean) / sqrtf(var + 1e-5f) * gamma[c0] + beta[c0];
        v[c0] = fmaxf(val, 0.f);
        mean = sums[c1] * invN;
        var = sumsq[c1] * invN - mean * mean;
        val = (bfhi(u) - mean) / sqrtf(var + 1e-5f) * gamma[c1] + beta[c1];
        v[c1] = fmaxf(val, 0.f);
    }
    __syncthreads();
    float r = 0.f;
    if (lane < 32) {
        float z = b1[lane];
        for (int c = 0; c < 128; c++) z += v[c] * W1[c * 32 + lane];
        z = z > 0.f ? z : 0.01f * z;
        r = z * W2[lane];
    }
#pragma unroll
    for (int off = 16; off >= 1; off >>= 1) r += __shfl_xor(r, off);
    if (lane == 0) out[blk] = r + b2[0];
}

// ---------------------------------------------------------------------------
extern "C" void kernel_launch(void* const* d_in, const int* in_sizes, int n_in,
                              void* d_out, int out_size, void* d_ws, size_t ws_size,
                              hipStream_t stream) {
    const float* x     = (const float*)d_in[0];
    const int*   edges = (const int*)d_in[1];
    const int*   lut   = (const int*)d_in[2];
    const float* W_lin = (const float*)d_in[3];
    const float* att_s = (const float*)d_in[4];
    const float* att_d = (const float*)d_in[5];
    const float* bias  = (const float*)d_in[6];
    const float* gamma = (const float*)d_in[7];
    const float* beta  = (const float*)d_in[8];
    const float* W1    = (const float*)d_in[9];
    const float* b1    = (const float*)d_in[10];
    const float* W2    = (const float*)d_in[11];
    const float* b2    = (const float*)d_in[12];

    int N = in_sizes[0] / 16;
    int E = in_sizes[1] / 2;
    int nlut = in_sizes[2];
    int B = (N + 255) >> BSHIFT;   // 391 for N=100000

    const int* esrc = edges;
    const int* edst = edges + E;

    char* ws = (char*)d_ws;
    size_t off = 0;
    auto alloc = [&](size_t bytes) -> void* {
        void* p = ws + off;
        off += (bytes + 255) & ~(size_t)255;
        return p;
    };
    uint*  h       = (uint*)alloc((size_t)N * 64 * 4);          // bf16x2 [N,128]
    uint*  hagg    = (uint*)alloc((size_t)N * 64 * 4);          // bf16x2 [N,128]
    float* a_src   = (float*)alloc((size_t)N * 4 * 4);
    float* a_dst   = (float*)alloc((size_t)N * 4 * 4);
    int*   offsets = (int*)alloc((size_t)N * 4);
    int*   degs    = (int*)alloc((size_t)N * 4);
    int*   sorted  = (int*)alloc((size_t)B * SORT_CAP * 4);
    uint2* wsorted = (uint2*)alloc((size_t)B * SORT_CAP * 8);   // fp16x4 weights
    uint*  pairs   = (uint*)alloc((size_t)B * SORT_CAP * 4);
    int*   cursor  = (int*)alloc((size_t)NBUCK * 4);
    float* sums    = (float*)alloc(128 * 4);
    float* sumsq   = (float*)alloc(128 * 4);
    float* WsWd    = (float*)alloc(128 * 4);

    k_prep<<<1, 128, 0, stream>>>(W_lin, att_s, att_d, WsWd, cursor, sums, sumsq);
    k_linear<<<(N + 31) / 32, 256, 0, stream>>>(x, W_lin, WsWd, h, a_src, a_dst, N);
    kb_scatter<<<(E + TILE - 1) / TILE, SCAT_T, 0, stream>>>(esrc, edst, E, cursor, pairs);
    kb_sort<<<B, SORT_T, 0, stream>>>(pairs, cursor, a_src, a_dst, N,
                                      sorted, wsorted, offsets, degs);
    k_gat<<<(N + 15) / 16, 256, 0, stream>>>(offsets, degs, sorted, wsorted, h,
                                             a_src, a_dst, bias, hagg, N);
    k_bnstats<<<256, 256, 0, stream>>>(hagg, N, sums, sumsq);
    k_mlp<<<nlut, 64, 0, stream>>>(hagg, lut, sums, sumsq, gamma, beta, W1, b1, W2, b2,
                                   (float*)d_out, N, nlut);
}